// Round 3
// baseline (280.556 us; speedup 1.0000x reference)
//
#include <hip/hip_runtime.h>
#include <math.h>

// Problem constants: h [B,T,D] fp32, k scalar fp32.
#define BB 8
#define TT 2048
#define DD 512
#define LL 16             // chunk length (t-steps)
#define CC (TT / LL)      // 128 chunks per b
#define D4 (DD / 4)       // 128 float4 lanes = block size
#define SCT 64            // superchunk length (t-steps)
#define NSC (TT / SCT)    // 32 superchunks per b
#define CPS (SCT / LL)    // 4 chunks per superchunk

typedef float floatx4 __attribute__((ext_vector_type(4)));

__device__ __forceinline__ float get_s(const float* kp) {
    float k = *kp;
    return (k > 20.0f) ? k : log1pf(expf(k));   // softplus, stable
}

// Poison-proof ready token: (lo = idx+1, hi = ~lo). A uniform 32-bit fill
// pattern P would need P == lo AND P == ~lo -> impossible. Token is also
// deterministic per slot -> protocol is idempotent across re-runs.
__device__ __forceinline__ unsigned long long mk_tok(unsigned idx) {
    unsigned lo = idx + 1u;
    return ((unsigned long long)(~lo) << 32) | (unsigned long long)lo;
}

// ---------------------------------------------------------------------------
// Fused single-dispatch kernel, REGULAR launch (graph-capturable; R2's
// cooperative launch never ran under capture -> output stayed zero).
// Grid = 8*128 = 1024 blocks x 128 threads, __launch_bounds__(128,2) caps
// VGPR<=256 so all 1024 blocks (2 waves each) are co-resident (>=4/CU).
//
// Producer/consumer flag protocol (all waits target LOWER block indices):
//  A : every block computes its chunk (16 t) stats from h held in REGISTERS,
//      writes csum/cend, fence+barrier, release-stores flagC[b,c].
//  A2: blocks with c%4==3 spin on their 3 sibling flagC, fold superchunk
//      stats (same accumulation order as old kA), release-store flagS[b,sc].
//  B : all blocks spin wave-parallel on flagS[0..sc-1] + sibling flagC,
//      acquire-fence, then R1's proven batched clamped lookback + cumsum +
//      wave butterfly + ctx recurrence from registers, non-temporal store.
//
// vs R1: h read ONCE from HBM, one dispatch instead of two.
// ---------------------------------------------------------------------------
__global__ __launch_bounds__(D4, 2) void kFused(
    const float* __restrict__ h, const float* __restrict__ kp,
    float* __restrict__ csum, float* __restrict__ cend,
    float* __restrict__ ssum, float* __restrict__ send,
    unsigned long long* __restrict__ flagC,
    unsigned long long* __restrict__ flagS,
    float* __restrict__ out)
{
    const int blk = blockIdx.x;
    const int b = blk / CC, c = blk % CC;
    const int sc = c / CPS, j = c & (CPS - 1);
    const int tid = threadIdx.x;
    const int wave = tid >> 6, lane = tid & 63;
    const float s   = get_s(kp);
    const float a   = expf(-s);
    const float a16 = expf(-s * (float)LL);
    const float aSC = expf(-s * (float)SCT);

    const int t0 = c * LL;
    const float4* hp = reinterpret_cast<const float4*>(h)
                     + (size_t)(b * TT + t0) * D4 + tid;

    __shared__ float part[2][LL];

    // ---- phase A: chunk -> registers, chunk stats, publish ---------------
    float4 hv[LL];                                   // 64 VGPRs
    float sx = 0.f, sy = 0.f, sz = 0.f, sw = 0.f;    // chunk sum
    float ex = 0.f, ey = 0.f, ez = 0.f, ew = 0.f;    // chunk decayed end
    #pragma unroll
    for (int i = 0; i < LL; i++) {
        float4 x = hp[(size_t)i * D4];
        hv[i] = x;
        sx += x.x; sy += x.y; sz += x.z; sw += x.w;
        ex = fmaf(a, ex, x.x);
        ey = fmaf(a, ey, x.y);
        ez = fmaf(a, ez, x.z);
        ew = fmaf(a, ew, x.w);
    }
    {
        const size_t ci = (size_t)(b * CC + c) * D4 + tid;
        reinterpret_cast<float4*>(csum)[ci] = make_float4(sx, sy, sz, sw);
        reinterpret_cast<float4*>(cend)[ci] = make_float4(ex, ey, ez, ew);
    }

    float px = 0.f, py = 0.f, pz = 0.f, pw = 0.f;    // h[t0-1]
    if (t0 > 0) {
        float4 pv = *(hp - (ptrdiff_t)D4);
        px = pv.x; py = pv.y; pz = pv.z; pw = pv.w;
    }

    __threadfence();       // each wave: make csum/cend agent-visible
    __syncthreads();       // both waves' fences happen-before the flag store
    if (tid == 0) {
        __hip_atomic_store(&flagC[(unsigned)(b * CC + c)],
                           mk_tok((unsigned)(b * CC + c)),
                           __ATOMIC_RELEASE, __HIP_MEMORY_SCOPE_AGENT);
    }

    // ---- phase A2: superchunk fold (last chunk of each superchunk) -------
    if ((c & (CPS - 1)) == (CPS - 1)) {
        const int base = b * CC + sc * CPS;
        // wave-parallel spin on 3 sibling chunk flags (lanes 0..2)
        {
            const int q = (lane < CPS - 1) ? lane : 0;
            const unsigned long long* fa = &flagC[(unsigned)(base + q)];
            const unsigned long long ex_ = mk_tok((unsigned)(base + q));
            const bool need = (lane < CPS - 1);
            for (;;) {
                unsigned long long v = need
                    ? __hip_atomic_load(fa, __ATOMIC_RELAXED, __HIP_MEMORY_SCOPE_AGENT)
                    : ex_;
                if (__all(v == ex_)) break;
                __builtin_amdgcn_s_sleep(2);
            }
            __threadfence();   // acquire side
        }
        const float4* cs4 = reinterpret_cast<const float4*>(csum)
                          + (size_t)base * D4 + tid;
        const float4* ce4 = reinterpret_cast<const float4*>(cend)
                          + (size_t)base * D4 + tid;
        float Sx = 0.f, Sy = 0.f, Sz = 0.f, Sw = 0.f;
        float Ex = 0.f, Ey = 0.f, Ez = 0.f, Ew = 0.f;
        #pragma unroll
        for (int q = 0; q < CPS - 1; q++) {          // siblings 0..2
            float4 sv = cs4[(size_t)q * D4];
            float4 ev = ce4[(size_t)q * D4];
            Sx += sv.x; Sy += sv.y; Sz += sv.z; Sw += sv.w;
            Ex = fmaf(a16, Ex, ev.x);
            Ey = fmaf(a16, Ey, ev.y);
            Ez = fmaf(a16, Ez, ev.z);
            Ew = fmaf(a16, Ew, ev.w);
        }
        // own chunk (q = 3) from registers, same fold order as old kA
        Sx += sx; Sy += sy; Sz += sz; Sw += sw;
        Ex = fmaf(a16, Ex, ex);
        Ey = fmaf(a16, Ey, ey);
        Ez = fmaf(a16, Ez, ez);
        Ew = fmaf(a16, Ew, ew);

        const size_t si = (size_t)(b * NSC + sc) * D4 + tid;
        reinterpret_cast<float4*>(ssum)[si] = make_float4(Sx, Sy, Sz, Sw);
        reinterpret_cast<float4*>(send)[si] = make_float4(Ex, Ey, Ez, Ew);

        __threadfence();
        __syncthreads();
        if (tid == 0) {
            __hip_atomic_store(&flagS[(unsigned)(b * NSC + sc)],
                               mk_tok((unsigned)(b * NSC + sc)),
                               __ATOMIC_RELEASE, __HIP_MEMORY_SCOPE_AGENT);
        }
    }

    // ---- phase B gate: wave-parallel spin on needed flags ----------------
    // lanes 0..30  -> flagS[b, p] for p < sc
    // lanes 32..34 -> flagC[b, sc*CPS + q] for q < j
    {
        const bool needS = (lane < NSC - 1) && (lane < sc);
        const bool needC = (lane >= 32) && (lane < 32 + CPS - 1)
                         && ((lane - 32) < j);
        const unsigned fsIdx = (unsigned)(b * NSC + ((lane < NSC - 1) ? lane : 0));
        const unsigned fcIdx = (unsigned)(b * CC + sc * CPS
                             + ((lane >= 32 && lane < 32 + CPS - 1) ? (lane - 32) : 0));
        const unsigned long long* fa = (lane < NSC - 1) ? &flagS[fsIdx] : &flagC[fcIdx];
        const unsigned long long ex_ = (lane < NSC - 1) ? mk_tok(fsIdx) : mk_tok(fcIdx);
        const bool need = needS || needC;
        if (__any(need)) {
            for (;;) {
                unsigned long long v = need
                    ? __hip_atomic_load(fa, __ATOMIC_RELAXED, __HIP_MEMORY_SCOPE_AGENT)
                    : ex_;
                if (__all(v == ex_)) break;
                __builtin_amdgcn_s_sleep(2);
            }
            __threadfence();   // acquire side before stats reads
        }
    }

    // ---- lookback level 1: superchunks before sc (batched, clamped) ------
    float cox = 0.f, coy = 0.f, coz = 0.f, cow = 0.f;   // cumsum offset
    float ccx = 0.f, ccy = 0.f, ccz = 0.f, ccw = 0.f;   // ctx entering state
    if (sc > 0) {
        const float4* ss4 = reinterpret_cast<const float4*>(ssum)
                          + (size_t)(b * NSC) * D4 + tid;
        const float4* se4 = reinterpret_cast<const float4*>(send)
                          + (size_t)(b * NSC) * D4 + tid;
        float w = 1.f;                      // aSC^d (descending weights)
        #pragma unroll
        for (int d = 0; d < NSC - 1; d++) {
            const int   q    = (d < sc) ? (sc - 1 - d) : 0;   // clamped addr
            const float live = (d < sc) ? 1.f : 0.f;
            float4 sv = ss4[(size_t)q * D4];
            float4 ev = se4[(size_t)q * D4];
            cox = fmaf(live, sv.x, cox);
            coy = fmaf(live, sv.y, coy);
            coz = fmaf(live, sv.z, coz);
            cow = fmaf(live, sv.w, cow);
            const float wl = w * live;
            ccx = fmaf(wl, ev.x, ccx);
            ccy = fmaf(wl, ev.y, ccy);
            ccz = fmaf(wl, ev.z, ccz);
            ccw = fmaf(wl, ev.w, ccw);
            w *= aSC;
        }
    }
    // ---- lookback level 2: chunks before j inside superchunk sc (<=3) ----
    if (j > 0) {
        const float4* cs4 = reinterpret_cast<const float4*>(csum)
                          + (size_t)(b * CC + sc * CPS) * D4 + tid;
        const float4* ce4 = reinterpret_cast<const float4*>(cend)
                          + (size_t)(b * CC + sc * CPS) * D4 + tid;
        float cIx = 0.f, cIy = 0.f, cIz = 0.f, cIw = 0.f;
        float w = 1.f;                      // a16^d (descending weights)
        #pragma unroll
        for (int d = 0; d < CPS - 1; d++) {
            const int   q    = (d < j) ? (j - 1 - d) : 0;     // clamped addr
            const float live = (d < j) ? 1.f : 0.f;
            float4 sv = cs4[(size_t)q * D4];
            float4 ev = ce4[(size_t)q * D4];
            cox = fmaf(live, sv.x, cox);
            coy = fmaf(live, sv.y, coy);
            coz = fmaf(live, sv.z, coz);
            cow = fmaf(live, sv.w, cow);
            const float wl = w * live;
            cIx = fmaf(wl, ev.x, cIx);
            cIy = fmaf(wl, ev.y, cIy);
            cIz = fmaf(wl, ev.z, cIz);
            cIw = fmaf(wl, ev.w, cIw);
            w *= a16;
        }
        // ctx entering chunk = (superchunk carry) * a16^j + intra part
        const float a32 = a16 * a16;
        const float wj  = (j == 1) ? a16 : (j == 2) ? a32 : a32 * a16;
        ccx = fmaf(wj, ccx, cIx);
        ccy = fmaf(wj, ccy, cIy);
        ccz = fmaf(wj, ccz, cIz);
        ccw = fmaf(wj, ccw, cIw);
    }

    // ---- pass A: cumsum chain from registers -----------------------------
    float r[LL];
    #pragma unroll
    for (int i = 0; i < LL; i++) {
        float4 x = hv[i];
        cox += x.x; coy += x.y; coz += x.z; cow += x.w;
        float dx = cox - px, dy = coy - py, dz = coz - pz, dw = cow - pw;
        r[i] = dx * dx + dy * dy + dz * dz + dw * dw;
        px = x.x; py = x.y; pz = x.z; pw = x.w;
    }

    // batched butterfly: 6 rounds x 16 independent values
    #pragma unroll
    for (int m = 1; m < 64; m <<= 1) {
        #pragma unroll
        for (int i = 0; i < LL; i++) r[i] += __shfl_xor(r[i], m, 64);
    }
    if (lane == 0) {
        #pragma unroll
        for (int i = 0; i < LL; i++) part[wave][i] = r[i];
    }
    __syncthreads();

    float mag[LL];
    #pragma unroll
    for (int i = 0; i < LL; i++) mag[i] = sqrtf(part[0][i] + part[1][i]);

    // ---- pass B: ctx recurrence from registers, non-temporal store -------
    floatx4* op = reinterpret_cast<floatx4*>(out)
                + (size_t)(b * TT + t0) * D4 + tid;
    #pragma unroll
    for (int i = 0; i < LL; i++) {
        float4 x = hv[i];
        ccx = fmaf(a, ccx, x.x);
        ccy = fmaf(a, ccy, x.y);
        ccz = fmaf(a, ccz, x.z);
        ccw = fmaf(a, ccw, x.w);
        float m = mag[i];
        floatx4 o;
        o.x = fabsf(m * ccx); o.y = fabsf(m * ccy);
        o.z = fabsf(m * ccz); o.w = fabsf(m * ccw);
        __builtin_nontemporal_store(o, op + (size_t)i * D4);
    }
}

extern "C" void kernel_launch(void* const* d_in, const int* in_sizes, int n_in,
                              void* d_out, int out_size, void* d_ws, size_t ws_size,
                              hipStream_t stream) {
    const float* h  = (const float*)d_in[0];
    const float* kp = (const float*)d_in[1];
    float* out = (float*)d_out;

    const size_t NC  = (size_t)BB * CC * DD;    // 512K floats = 2 MB each
    const size_t NSb = (size_t)BB * NSC * DD;   // 128K floats = 512 KB each
    float* csum = (float*)d_ws;
    float* cend = csum + NC;
    float* ssum = cend + NC;
    float* send = ssum + NSb;
    unsigned long long* flagC =
        (unsigned long long*)(send + NSb);                  // 8B-aligned
    unsigned long long* flagS = flagC + (size_t)BB * CC;

    kFused<<<dim3(BB * CC), dim3(D4), 0, stream>>>(
        h, kp, csum, cend, ssum, send, flagC, flagS, out);
}

// Round 4
// 101.189 us; speedup vs baseline: 2.7726x; 2.7726x over previous
//
#include <hip/hip_runtime.h>
#include <math.h>

// Problem constants: h [B,T,D] fp32, k scalar fp32.
#define BB 8
#define TT 2048
#define DD 512
#define LL 16             // chunk length (t-steps)
#define CC (TT / LL)      // 128 chunks per b
#define D4 (DD / 4)       // 128 float4 lanes
#define SCT 64            // superchunk length (t-steps)
#define NSC (TT / SCT)    // 32 superchunks per b
#define CPS (SCT / LL)    // 4 chunks per superchunk

typedef float floatx4 __attribute__((ext_vector_type(4)));

__device__ __forceinline__ float get_s(const float* kp) {
    float k = *kp;
    return (k > 20.0f) ? k : log1pf(expf(k));   // softplus, stable
}

// ---------------------------------------------------------------------------
// Kernel A (R4): block = (b, superchunk) with 512 THREADS (8 waves).
// The 4 chunk recurrences inside a superchunk are independent, so each
// 128-thread group (jj = tid>>7) owns one 16-t chunk: dependent-load chain
// shrinks 64 -> 16 and TLP goes 2 -> 8 waves/CU (old kA was 0.5 waves/SIMD,
// pure HBM-latency-bound). Superchunk stats are folded through 16 KB LDS in
// the same j-order as the old serial fold.
// Grid = 8*32 = 256 blocks x 512 threads = 1 block/CU.
// ---------------------------------------------------------------------------
__global__ __launch_bounds__(4 * D4) void kA_stats(
    const float* __restrict__ h, const float* __restrict__ kp,
    float* __restrict__ csum, float* __restrict__ cend,
    float* __restrict__ ssum, float* __restrict__ send)
{
    const int blk = blockIdx.x;
    const int b = blk / NSC, sc = blk % NSC;
    const int tid = threadIdx.x;
    const int jj  = tid >> 7;          // chunk within superchunk, 0..3
    const int col = tid & (D4 - 1);    // float4 column, 0..127
    const float s   = get_s(kp);
    const float a   = expf(-s);
    const float a16 = expf(-s * (float)LL);

    const float4* hp = reinterpret_cast<const float4*>(h)
                     + (size_t)(b * TT + sc * SCT + jj * LL) * D4 + col;

    float sx = 0.f, sy = 0.f, sz = 0.f, sw = 0.f;   // chunk sum
    float ex = 0.f, ey = 0.f, ez = 0.f, ew = 0.f;   // chunk decayed end
    #pragma unroll
    for (int i = 0; i < LL; i++) {
        float4 x = hp[(size_t)i * D4];
        sx += x.x; sy += x.y; sz += x.z; sw += x.w;
        ex = fmaf(a, ex, x.x);
        ey = fmaf(a, ey, x.y);
        ez = fmaf(a, ez, x.z);
        ew = fmaf(a, ew, x.w);
    }
    {
        const size_t ci = (size_t)(b * CC + sc * CPS + jj) * D4 + col;
        reinterpret_cast<float4*>(csum)[ci] = make_float4(sx, sy, sz, sw);
        reinterpret_cast<float4*>(cend)[ci] = make_float4(ex, ey, ez, ew);
    }

    // ---- superchunk fold via LDS (same j-order as old serial kA) ---------
    __shared__ float4 lsum[CPS][D4];   // 8 KB
    __shared__ float4 lend[CPS][D4];   // 8 KB
    lsum[jj][col] = make_float4(sx, sy, sz, sw);
    lend[jj][col] = make_float4(ex, ey, ez, ew);
    __syncthreads();

    if (jj == 0) {
        float Sx = 0.f, Sy = 0.f, Sz = 0.f, Sw = 0.f;
        float Ex = 0.f, Ey = 0.f, Ez = 0.f, Ew = 0.f;
        #pragma unroll
        for (int q = 0; q < CPS; q++) {
            float4 sv = lsum[q][col];
            float4 ev = lend[q][col];
            Sx += sv.x; Sy += sv.y; Sz += sv.z; Sw += sv.w;
            Ex = fmaf(a16, Ex, ev.x);
            Ey = fmaf(a16, Ey, ev.y);
            Ez = fmaf(a16, Ez, ev.z);
            Ew = fmaf(a16, Ew, ev.w);
        }
        const size_t si = (size_t)(b * NSC + sc) * D4 + col;
        reinterpret_cast<float4*>(ssum)[si] = make_float4(Sx, Sy, Sz, Sw);
        reinterpret_cast<float4*>(send)[si] = make_float4(Ex, Ey, Ez, Ew);
    }
}

// ---------------------------------------------------------------------------
// Kernel B (R4): block = (b, chunk), 128 threads, REGISTER-resident h
// (hv[16] = 64 VGPRs; numerics verbatim from R3's passing phase B). No LDS
// stash -> occupancy is VGPR-bound: ~100 VGPRs @ launch_bounds(128,4) gives
// ~4-5 waves/SIMD (~8-10 blocks/CU) vs the old DMA version's LDS-capped 4.
// The 16 h loads + up to 62 lookback stat loads form one independent batch
// the scheduler pipelines under counted vmcnt.
// Grid = 8*128 = 1024 blocks x 128 threads.
// ---------------------------------------------------------------------------
__global__ __launch_bounds__(D4, 4) void kB_out(
    const float* __restrict__ h, const float* __restrict__ kp,
    const float* __restrict__ csum, const float* __restrict__ cend,
    const float* __restrict__ ssum, const float* __restrict__ send,
    float* __restrict__ out)
{
    const int blk = blockIdx.x;
    const int b = blk / CC, c = blk % CC;
    const int sc = c / CPS, j = c & (CPS - 1);
    const int tid = threadIdx.x;
    const int wave = tid >> 6, lane = tid & 63;
    const float s   = get_s(kp);
    const float a   = expf(-s);
    const float a16 = expf(-s * (float)LL);
    const float aSC = expf(-s * (float)SCT);

    const int t0 = c * LL;
    const float4* hp = reinterpret_cast<const float4*>(h)
                     + (size_t)(b * TT + t0) * D4 + tid;

    __shared__ float part[2][LL];

    // ---- h chunk -> registers (independent batch, pipelines w/ lookback) -
    float4 hv[LL];                                   // 64 VGPRs
    #pragma unroll
    for (int i = 0; i < LL; i++) hv[i] = hp[(size_t)i * D4];

    float px = 0.f, py = 0.f, pz = 0.f, pw = 0.f;    // h[t0-1]
    if (t0 > 0) {
        float4 pv = *(hp - (ptrdiff_t)D4);
        px = pv.x; py = pv.y; pz = pv.z; pw = pv.w;
    }

    // ---- lookback level 1: superchunks before sc (batched, clamped) ------
    float cox = 0.f, coy = 0.f, coz = 0.f, cow = 0.f;   // cumsum offset
    float ccx = 0.f, ccy = 0.f, ccz = 0.f, ccw = 0.f;   // ctx entering state
    if (sc > 0) {
        const float4* ss4 = reinterpret_cast<const float4*>(ssum)
                          + (size_t)(b * NSC) * D4 + tid;
        const float4* se4 = reinterpret_cast<const float4*>(send)
                          + (size_t)(b * NSC) * D4 + tid;
        float w = 1.f;                      // aSC^d (descending weights)
        #pragma unroll
        for (int d = 0; d < NSC - 1; d++) {
            const int   q    = (d < sc) ? (sc - 1 - d) : 0;   // clamped addr
            const float live = (d < sc) ? 1.f : 0.f;
            float4 sv = ss4[(size_t)q * D4];
            float4 ev = se4[(size_t)q * D4];
            cox = fmaf(live, sv.x, cox);
            coy = fmaf(live, sv.y, coy);
            coz = fmaf(live, sv.z, coz);
            cow = fmaf(live, sv.w, cow);
            const float wl = w * live;
            ccx = fmaf(wl, ev.x, ccx);
            ccy = fmaf(wl, ev.y, ccy);
            ccz = fmaf(wl, ev.z, ccz);
            ccw = fmaf(wl, ev.w, ccw);
            w *= aSC;
        }
    }
    // ---- lookback level 2: chunks before j inside superchunk sc (<=3) ----
    if (j > 0) {
        const float4* cs4 = reinterpret_cast<const float4*>(csum)
                          + (size_t)(b * CC + sc * CPS) * D4 + tid;
        const float4* ce4 = reinterpret_cast<const float4*>(cend)
                          + (size_t)(b * CC + sc * CPS) * D4 + tid;
        float cIx = 0.f, cIy = 0.f, cIz = 0.f, cIw = 0.f;
        float w = 1.f;                      // a16^d (descending weights)
        #pragma unroll
        for (int d = 0; d < CPS - 1; d++) {
            const int   q    = (d < j) ? (j - 1 - d) : 0;     // clamped addr
            const float live = (d < j) ? 1.f : 0.f;
            float4 sv = cs4[(size_t)q * D4];
            float4 ev = ce4[(size_t)q * D4];
            cox = fmaf(live, sv.x, cox);
            coy = fmaf(live, sv.y, coy);
            coz = fmaf(live, sv.z, coz);
            cow = fmaf(live, sv.w, cow);
            const float wl = w * live;
            cIx = fmaf(wl, ev.x, cIx);
            cIy = fmaf(wl, ev.y, cIy);
            cIz = fmaf(wl, ev.z, cIz);
            cIw = fmaf(wl, ev.w, cIw);
            w *= a16;
        }
        // ctx entering chunk = (superchunk carry) * a16^j + intra part
        const float a32 = a16 * a16;
        const float wj  = (j == 1) ? a16 : (j == 2) ? a32 : a32 * a16;
        ccx = fmaf(wj, ccx, cIx);
        ccy = fmaf(wj, ccy, cIy);
        ccz = fmaf(wj, ccz, cIz);
        ccw = fmaf(wj, ccw, cIw);
    }

    // ---- pass A: cumsum chain from registers -----------------------------
    float r[LL];
    #pragma unroll
    for (int i = 0; i < LL; i++) {
        float4 x = hv[i];
        cox += x.x; coy += x.y; coz += x.z; cow += x.w;
        float dx = cox - px, dy = coy - py, dz = coz - pz, dw = cow - pw;
        r[i] = dx * dx + dy * dy + dz * dz + dw * dw;
        px = x.x; py = x.y; pz = x.z; pw = x.w;
    }

    // batched butterfly: 6 rounds x 16 independent values
    #pragma unroll
    for (int m = 1; m < 64; m <<= 1) {
        #pragma unroll
        for (int i = 0; i < LL; i++) r[i] += __shfl_xor(r[i], m, 64);
    }
    if (lane == 0) {
        #pragma unroll
        for (int i = 0; i < LL; i++) part[wave][i] = r[i];
    }
    __syncthreads();

    float mag[LL];
    #pragma unroll
    for (int i = 0; i < LL; i++) mag[i] = sqrtf(part[0][i] + part[1][i]);

    // ---- pass B: ctx recurrence from registers, non-temporal store -------
    floatx4* op = reinterpret_cast<floatx4*>(out)
                + (size_t)(b * TT + t0) * D4 + tid;
    #pragma unroll
    for (int i = 0; i < LL; i++) {
        float4 x = hv[i];
        ccx = fmaf(a, ccx, x.x);
        ccy = fmaf(a, ccy, x.y);
        ccz = fmaf(a, ccz, x.z);
        ccw = fmaf(a, ccw, x.w);
        float m = mag[i];
        floatx4 o;
        o.x = fabsf(m * ccx); o.y = fabsf(m * ccy);
        o.z = fabsf(m * ccz); o.w = fabsf(m * ccw);
        __builtin_nontemporal_store(o, op + (size_t)i * D4);
    }
}

extern "C" void kernel_launch(void* const* d_in, const int* in_sizes, int n_in,
                              void* d_out, int out_size, void* d_ws, size_t ws_size,
                              hipStream_t stream) {
    const float* h  = (const float*)d_in[0];
    const float* kp = (const float*)d_in[1];
    float* out = (float*)d_out;

    const size_t NC  = (size_t)BB * CC * DD;    // 512K floats = 2 MB each
    const size_t NSb = (size_t)BB * NSC * DD;   // 128K floats = 512 KB each
    float* csum = (float*)d_ws;
    float* cend = csum + NC;
    float* ssum = cend + NC;
    float* send = ssum + NSb;

    kA_stats<<<dim3(BB * NSC), dim3(4 * D4), 0, stream>>>(h, kp, csum, cend, ssum, send);
    kB_out  <<<dim3(BB * CC),  dim3(D4),     0, stream>>>(h, kp, csum, cend, ssum, send, out);
}

// Round 5
// 96.902 us; speedup vs baseline: 2.8953x; 1.0442x over previous
//
#include <hip/hip_runtime.h>
#include <math.h>

// Problem constants: h [B,T,D] fp32, k scalar fp32.
#define BB 8
#define TT 2048
#define DD 512
#define LL 16             // chunk length (t-steps)
#define CC (TT / LL)      // 128 chunks per b
#define D4 (DD / 4)       // 128 float4 lanes
#define SCT 64            // superchunk length (t-steps)
#define NSC (TT / SCT)    // 32 superchunks per b
#define CPS (SCT / LL)    // 4 chunks per superchunk

typedef float floatx4 __attribute__((ext_vector_type(4)));

__device__ __forceinline__ float get_s(const float* kp) {
    float k = *kp;
    return (k > 20.0f) ? k : log1pf(expf(k));   // softplus, stable
}

// ---------------------------------------------------------------------------
// Kernel A (R4 version, kept): block = (b, superchunk), 512 THREADS (8 waves).
// The 4 chunk recurrences in a superchunk are independent: each 128-thread
// group (jj = tid>>7) owns one 16-t chunk -> dependent-load chain 64 -> 16,
// TLP 2 -> 8 waves/CU. Superchunk stats folded through 16 KB LDS in the same
// j-order as the old serial fold. Grid = 256 blocks x 512 threads.
// ---------------------------------------------------------------------------
__global__ __launch_bounds__(4 * D4) void kA_stats(
    const float* __restrict__ h, const float* __restrict__ kp,
    float* __restrict__ csum, float* __restrict__ cend,
    float* __restrict__ ssum, float* __restrict__ send)
{
    const int blk = blockIdx.x;
    const int b = blk / NSC, sc = blk % NSC;
    const int tid = threadIdx.x;
    const int jj  = tid >> 7;          // chunk within superchunk, 0..3
    const int col = tid & (D4 - 1);    // float4 column, 0..127
    const float s   = get_s(kp);
    const float a   = expf(-s);
    const float a16 = expf(-s * (float)LL);

    const float4* hp = reinterpret_cast<const float4*>(h)
                     + (size_t)(b * TT + sc * SCT + jj * LL) * D4 + col;

    float sx = 0.f, sy = 0.f, sz = 0.f, sw = 0.f;   // chunk sum
    float ex = 0.f, ey = 0.f, ez = 0.f, ew = 0.f;   // chunk decayed end
    #pragma unroll
    for (int i = 0; i < LL; i++) {
        float4 x = hp[(size_t)i * D4];
        sx += x.x; sy += x.y; sz += x.z; sw += x.w;
        ex = fmaf(a, ex, x.x);
        ey = fmaf(a, ey, x.y);
        ez = fmaf(a, ez, x.z);
        ew = fmaf(a, ew, x.w);
    }
    {
        const size_t ci = (size_t)(b * CC + sc * CPS + jj) * D4 + col;
        reinterpret_cast<float4*>(csum)[ci] = make_float4(sx, sy, sz, sw);
        reinterpret_cast<float4*>(cend)[ci] = make_float4(ex, ey, ez, ew);
    }

    // ---- superchunk fold via LDS (same j-order as old serial kA) ---------
    __shared__ float4 lsum[CPS][D4];   // 8 KB
    __shared__ float4 lend[CPS][D4];   // 8 KB
    lsum[jj][col] = make_float4(sx, sy, sz, sw);
    lend[jj][col] = make_float4(ex, ey, ez, ew);
    __syncthreads();

    if (jj == 0) {
        float Sx = 0.f, Sy = 0.f, Sz = 0.f, Sw = 0.f;
        float Ex = 0.f, Ey = 0.f, Ez = 0.f, Ew = 0.f;
        #pragma unroll
        for (int q = 0; q < CPS; q++) {
            float4 sv = lsum[q][col];
            float4 ev = lend[q][col];
            Sx += sv.x; Sy += sv.y; Sz += sv.z; Sw += sv.w;
            Ex = fmaf(a16, Ex, ev.x);
            Ey = fmaf(a16, Ey, ev.y);
            Ez = fmaf(a16, Ez, ev.z);
            Ew = fmaf(a16, Ew, ev.w);
        }
        const size_t si = (size_t)(b * NSC + sc) * D4 + col;
        reinterpret_cast<float4*>(ssum)[si] = make_float4(Sx, Sy, Sz, Sw);
        reinterpret_cast<float4*>(send)[si] = make_float4(Ex, Ey, Ez, Ew);
    }
}

// ---------------------------------------------------------------------------
// Kernel B (VERBATIM from the 96.0 us R1 baseline): block = (b, chunk).
// h chunk fetched by async global->LDS DMA (width=16) issued BEFORE the
// lookback; L2-resident lookback overlaps the fetch. NO min-waves bound:
// R4's (128,4) capped VGPR at 128 and spilled the register-resident variant
// (VGPR needs ~100-130) -> scratch traffic regression. DMA+LDS version keeps
// VGPR low; LDS 32 KB -> 4 blocks/CU. Grid = 1024 blocks x 128 threads.
// ---------------------------------------------------------------------------
__global__ __launch_bounds__(D4) void kB_out(
    const float* __restrict__ h, const float* __restrict__ kp,
    const float* __restrict__ csum, const float* __restrict__ cend,
    const float* __restrict__ ssum, const float* __restrict__ send,
    float* __restrict__ out)
{
    const int blk = blockIdx.x;
    const int b = blk / CC, c = blk % CC;
    const int sc = c / CPS, j = c & (CPS - 1);
    const int tid = threadIdx.x;
    const int wave = tid >> 6, lane = tid & 63;
    const int w64 = wave << 6;              // wave-uniform LDS sub-base
    const float s   = get_s(kp);
    const float a   = expf(-s);
    const float a16 = expf(-s * (float)LL);
    const float aSC = expf(-s * (float)SCT);

    const int t0 = c * LL;
    const float4* hp = reinterpret_cast<const float4*>(h)
                     + (size_t)(b * TT + t0) * D4 + tid;

    __shared__ float4 stash[LL][D4];   // 32 KB chunk stash
    __shared__ float part[2][LL];

    // ---- async DMA: h chunk -> LDS, no VGPR round-trip; overlaps lookback
    #pragma unroll
    for (int i = 0; i < LL; i++) {
        __builtin_amdgcn_global_load_lds(
            (const __attribute__((address_space(1))) void*)(hp + (size_t)i * D4),
            (__attribute__((address_space(3))) void*)(&stash[i][w64]),
            16, 0, 0);
    }

    float px = 0.f, py = 0.f, pz = 0.f, pw = 0.f;   // h[t0-1]
    if (t0 > 0) {
        float4 pv = *(hp - (ptrdiff_t)D4);
        px = pv.x; py = pv.y; pz = pv.z; pw = pv.w;
    }

    // ---- lookback level 1: superchunks before sc (batched, clamped) ------
    float cox = 0.f, coy = 0.f, coz = 0.f, cow = 0.f;   // cumsum offset
    float ccx = 0.f, ccy = 0.f, ccz = 0.f, ccw = 0.f;   // ctx entering state
    if (sc > 0) {
        const float4* ss4 = reinterpret_cast<const float4*>(ssum)
                          + (size_t)(b * NSC) * D4 + tid;
        const float4* se4 = reinterpret_cast<const float4*>(send)
                          + (size_t)(b * NSC) * D4 + tid;
        float w = 1.f;                      // aSC^d (descending weights)
        #pragma unroll
        for (int d = 0; d < NSC - 1; d++) {
            const int   q    = (d < sc) ? (sc - 1 - d) : 0;   // clamped addr
            const float live = (d < sc) ? 1.f : 0.f;
            float4 sv = ss4[(size_t)q * D4];
            float4 ev = se4[(size_t)q * D4];
            cox = fmaf(live, sv.x, cox);
            coy = fmaf(live, sv.y, coy);
            coz = fmaf(live, sv.z, coz);
            cow = fmaf(live, sv.w, cow);
            const float wl = w * live;
            ccx = fmaf(wl, ev.x, ccx);
            ccy = fmaf(wl, ev.y, ccy);
            ccz = fmaf(wl, ev.z, ccz);
            ccw = fmaf(wl, ev.w, ccw);
            w *= aSC;
        }
    }
    // ---- lookback level 2: chunks before j inside superchunk sc (<=3) ----
    if (j > 0) {
        const float4* cs4 = reinterpret_cast<const float4*>(csum)
                          + (size_t)(b * CC + sc * CPS) * D4 + tid;
        const float4* ce4 = reinterpret_cast<const float4*>(cend)
                          + (size_t)(b * CC + sc * CPS) * D4 + tid;
        float cIx = 0.f, cIy = 0.f, cIz = 0.f, cIw = 0.f;
        float w = 1.f;                      // a16^d (descending weights)
        #pragma unroll
        for (int d = 0; d < CPS - 1; d++) {
            const int   q    = (d < j) ? (j - 1 - d) : 0;     // clamped addr
            const float live = (d < j) ? 1.f : 0.f;
            float4 sv = cs4[(size_t)q * D4];
            float4 ev = ce4[(size_t)q * D4];
            cox = fmaf(live, sv.x, cox);
            coy = fmaf(live, sv.y, coy);
            coz = fmaf(live, sv.z, coz);
            cow = fmaf(live, sv.w, cow);
            const float wl = w * live;
            cIx = fmaf(wl, ev.x, cIx);
            cIy = fmaf(wl, ev.y, cIy);
            cIz = fmaf(wl, ev.z, cIz);
            cIw = fmaf(wl, ev.w, cIw);
            w *= a16;
        }
        // ctx entering chunk = (superchunk carry) * a16^j + intra part
        const float a32 = a16 * a16;
        const float wj  = (j == 1) ? a16 : (j == 2) ? a32 : a32 * a16;
        ccx = fmaf(wj, ccx, cIx);
        ccy = fmaf(wj, ccy, cIy);
        ccz = fmaf(wj, ccz, cIz);
        ccw = fmaf(wj, ccw, cIw);
    }

    __syncthreads();   // drains the DMA (vmcnt) before LDS reads

    // ---- pass A: cumsum chain from LDS
    float r[LL];
    #pragma unroll
    for (int i = 0; i < LL; i++) {
        float4 x = stash[i][tid];
        cox += x.x; coy += x.y; coz += x.z; cow += x.w;
        float dx = cox - px, dy = coy - py, dz = coz - pz, dw = cow - pw;
        r[i] = dx * dx + dy * dy + dz * dz + dw * dw;
        px = x.x; py = x.y; pz = x.z; pw = x.w;
    }

    // batched butterfly: 6 rounds x 16 independent values
    #pragma unroll
    for (int m = 1; m < 64; m <<= 1) {
        #pragma unroll
        for (int i = 0; i < LL; i++) r[i] += __shfl_xor(r[i], m, 64);
    }
    if (lane == 0) {
        #pragma unroll
        for (int i = 0; i < LL; i++) part[wave][i] = r[i];
    }
    __syncthreads();

    float mag[LL];
    #pragma unroll
    for (int i = 0; i < LL; i++) mag[i] = sqrtf(part[0][i] + part[1][i]);

    // ---- pass B: ctx recurrence from LDS, non-temporal output store
    floatx4* op = reinterpret_cast<floatx4*>(out)
                + (size_t)(b * TT + t0) * D4 + tid;
    #pragma unroll
    for (int i = 0; i < LL; i++) {
        float4 x = stash[i][tid];
        ccx = fmaf(a, ccx, x.x);
        ccy = fmaf(a, ccy, x.y);
        ccz = fmaf(a, ccz, x.z);
        ccw = fmaf(a, ccw, x.w);
        float m = mag[i];
        floatx4 o;
        o.x = fabsf(m * ccx); o.y = fabsf(m * ccy);
        o.z = fabsf(m * ccz); o.w = fabsf(m * ccw);
        __builtin_nontemporal_store(o, op + (size_t)i * D4);
    }
}

extern "C" void kernel_launch(void* const* d_in, const int* in_sizes, int n_in,
                              void* d_out, int out_size, void* d_ws, size_t ws_size,
                              hipStream_t stream) {
    const float* h  = (const float*)d_in[0];
    const float* kp = (const float*)d_in[1];
    float* out = (float*)d_out;

    const size_t NC  = (size_t)BB * CC * DD;    // 512K floats = 2 MB each
    const size_t NSb = (size_t)BB * NSC * DD;   // 128K floats = 512 KB each
    float* csum = (float*)d_ws;
    float* cend = csum + NC;
    float* ssum = cend + NC;
    float* send = ssum + NSb;

    kA_stats<<<dim3(BB * NSC), dim3(4 * D4), 0, stream>>>(h, kp, csum, cend, ssum, send);
    kB_out  <<<dim3(BB * CC),  dim3(D4),     0, stream>>>(h, kp, csum, cend, ssum, send, out);
}

// Round 6
// 93.662 us; speedup vs baseline: 2.9954x; 1.0346x over previous
//
#include <hip/hip_runtime.h>
#include <math.h>

// Problem constants: h [B,T,D] fp32, k scalar fp32.
#define BB 8
#define TT 2048
#define DD 512
#define LL 16             // chunk length (t-steps)
#define CC (TT / LL)      // 128 chunks per b
#define D4 (DD / 4)       // 128 float4 lanes
#define SCT 64            // superchunk length (t-steps)
#define NSC (TT / SCT)    // 32 superchunks per b
#define CPS (SCT / LL)    // 4 chunks per superchunk

typedef float floatx4 __attribute__((ext_vector_type(4)));

__device__ __forceinline__ float get_s(const float* kp) {
    float k = *kp;
    return (k > 20.0f) ? k : log1pf(expf(k));   // softplus, stable
}

// ---------------------------------------------------------------------------
// Kernel A (R6): block = (b, superchunk), 512 threads (8 waves, 1 block/CU).
// Each 128-thread group jj computes chunk jj's stats; LDS fold -> superchunk
// ssum/send only (csum/cend no longer exist: kB now rebuilds chunk stats
// in-block). Grid = 256 x 512.
// ---------------------------------------------------------------------------
__global__ __launch_bounds__(4 * D4) void kA_stats(
    const float* __restrict__ h, const float* __restrict__ kp,
    float* __restrict__ ssum, float* __restrict__ send)
{
    const int blk = blockIdx.x;
    const int b = blk / NSC, sc = blk % NSC;
    const int tid = threadIdx.x;
    const int jj  = tid >> 7;          // chunk within superchunk, 0..3
    const int col = tid & (D4 - 1);    // float4 column, 0..127
    const float s   = get_s(kp);
    const float a   = expf(-s);
    const float a16 = expf(-s * (float)LL);

    const float4* hp = reinterpret_cast<const float4*>(h)
                     + (size_t)(b * TT + sc * SCT + jj * LL) * D4 + col;

    float sx = 0.f, sy = 0.f, sz = 0.f, sw = 0.f;   // chunk sum
    float ex = 0.f, ey = 0.f, ez = 0.f, ew = 0.f;   // chunk decayed end
    #pragma unroll
    for (int i = 0; i < LL; i++) {
        float4 x = hp[(size_t)i * D4];
        sx += x.x; sy += x.y; sz += x.z; sw += x.w;
        ex = fmaf(a, ex, x.x);
        ey = fmaf(a, ey, x.y);
        ez = fmaf(a, ez, x.z);
        ew = fmaf(a, ew, x.w);
    }

    // ---- superchunk fold via LDS (same j-order as old serial fold) -------
    __shared__ float4 lsum[CPS][D4];   // 8 KB
    __shared__ float4 lend[CPS][D4];   // 8 KB
    lsum[jj][col] = make_float4(sx, sy, sz, sw);
    lend[jj][col] = make_float4(ex, ey, ez, ew);
    __syncthreads();

    if (jj == 0) {
        float Sx = 0.f, Sy = 0.f, Sz = 0.f, Sw = 0.f;
        float Ex = 0.f, Ey = 0.f, Ez = 0.f, Ew = 0.f;
        #pragma unroll
        for (int q = 0; q < CPS; q++) {
            float4 sv = lsum[q][col];
            float4 ev = lend[q][col];
            Sx += sv.x; Sy += sv.y; Sz += sv.z; Sw += sv.w;
            Ex = fmaf(a16, Ex, ev.x);
            Ey = fmaf(a16, Ey, ev.y);
            Ez = fmaf(a16, Ez, ev.z);
            Ew = fmaf(a16, Ew, ev.w);
        }
        const size_t si = (size_t)(b * NSC + sc) * D4 + col;
        reinterpret_cast<float4*>(ssum)[si] = make_float4(Sx, Sy, Sz, Sw);
        reinterpret_cast<float4*>(send)[si] = make_float4(Ex, Ey, Ez, Ew);
    }
}

// ---------------------------------------------------------------------------
// Kernel B (R6): block = (b, SUPERCHUNK), 512 threads, 1 block/CU.
// Group jj (128 threads) owns chunk jj: h in REGISTERS (hv[16], ~110 VGPR;
// bounds (512,2) caps at 256 -> no spill, no 32 KB stash). Chunk stats are
// recomputed in-block and shared via 16 KB LDS, so the chunk-level lookback
// reads LDS instead of L2 and csum/cend are gone from global. Superchunk
// lookback = proven clamped fixed-trip batch. Blocks: 1024 -> 256 (4x less
// per-block fixed cost). All fold orders identical to R5 -> bit-identical out.
// ---------------------------------------------------------------------------
__global__ __launch_bounds__(4 * D4, 2) void kB_out(
    const float* __restrict__ h, const float* __restrict__ kp,
    const float* __restrict__ ssum, const float* __restrict__ send,
    float* __restrict__ out)
{
    const int blk = blockIdx.x;
    const int b = blk / NSC, sc = blk % NSC;
    const int tid = threadIdx.x;
    const int jj  = tid >> 7;          // chunk within superchunk, 0..3
    const int col = tid & (D4 - 1);    // float4 column, 0..127
    const int gw   = (tid >> 6) & 1;   // wave within group, 0..1
    const int lane = tid & 63;
    const float s   = get_s(kp);
    const float a   = expf(-s);
    const float a16 = expf(-s * (float)LL);
    const float aSC = expf(-s * (float)SCT);

    const int t0 = sc * SCT + jj * LL;
    const float4* hp = reinterpret_cast<const float4*>(h)
                     + (size_t)(b * TT + t0) * D4 + col;

    __shared__ float4 lsum[CPS][D4];   // 8 KB: chunk sums
    __shared__ float4 lend[CPS][D4];   // 8 KB: chunk decayed ends
    __shared__ float part[CPS][2][LL]; // 512 B

    // ---- h chunk -> registers + chunk stats (same order as old kA) -------
    float4 hv[LL];                                   // 64 VGPRs
    float sx = 0.f, sy = 0.f, sz = 0.f, sw = 0.f;
    float ex = 0.f, ey = 0.f, ez = 0.f, ew = 0.f;
    #pragma unroll
    for (int i = 0; i < LL; i++) {
        float4 x = hp[(size_t)i * D4];
        hv[i] = x;
        sx += x.x; sy += x.y; sz += x.z; sw += x.w;
        ex = fmaf(a, ex, x.x);
        ey = fmaf(a, ey, x.y);
        ez = fmaf(a, ez, x.z);
        ew = fmaf(a, ew, x.w);
    }
    lsum[jj][col] = make_float4(sx, sy, sz, sw);
    lend[jj][col] = make_float4(ex, ey, ez, ew);

    float px = 0.f, py = 0.f, pz = 0.f, pw = 0.f;    // h[t0-1]
    if (t0 > 0) {
        float4 pv = *(hp - (ptrdiff_t)D4);
        px = pv.x; py = pv.y; pz = pv.z; pw = pv.w;
    }

    // ---- lookback level 1: superchunks before sc (batched, clamped) ------
    float cox = 0.f, coy = 0.f, coz = 0.f, cow = 0.f;   // cumsum offset
    float ccx = 0.f, ccy = 0.f, ccz = 0.f, ccw = 0.f;   // ctx entering state
    if (sc > 0) {
        const float4* ss4 = reinterpret_cast<const float4*>(ssum)
                          + (size_t)(b * NSC) * D4 + col;
        const float4* se4 = reinterpret_cast<const float4*>(send)
                          + (size_t)(b * NSC) * D4 + col;
        float w = 1.f;                      // aSC^d (descending weights)
        #pragma unroll
        for (int d = 0; d < NSC - 1; d++) {
            const int   q    = (d < sc) ? (sc - 1 - d) : 0;   // clamped addr
            const float live = (d < sc) ? 1.f : 0.f;
            float4 sv = ss4[(size_t)q * D4];
            float4 ev = se4[(size_t)q * D4];
            cox = fmaf(live, sv.x, cox);
            coy = fmaf(live, sv.y, coy);
            coz = fmaf(live, sv.z, coz);
            cow = fmaf(live, sv.w, cow);
            const float wl = w * live;
            ccx = fmaf(wl, ev.x, ccx);
            ccy = fmaf(wl, ev.y, ccy);
            ccz = fmaf(wl, ev.z, ccz);
            ccw = fmaf(wl, ev.w, ccw);
            w *= aSC;
        }
    }

    __syncthreads();   // chunk stats of all 4 groups visible in LDS

    // ---- lookback level 2: chunks before jj, from LDS (was L2) -----------
    if (jj > 0) {
        float cIx = 0.f, cIy = 0.f, cIz = 0.f, cIw = 0.f;
        float w = 1.f;                      // a16^d (descending weights)
        #pragma unroll
        for (int d = 0; d < CPS - 1; d++) {
            const int   q    = (d < jj) ? (jj - 1 - d) : 0;   // clamped addr
            const float live = (d < jj) ? 1.f : 0.f;
            float4 sv = lsum[q][col];
            float4 ev = lend[q][col];
            cox = fmaf(live, sv.x, cox);
            coy = fmaf(live, sv.y, coy);
            coz = fmaf(live, sv.z, coz);
            cow = fmaf(live, sv.w, cow);
            const float wl = w * live;
            cIx = fmaf(wl, ev.x, cIx);
            cIy = fmaf(wl, ev.y, cIy);
            cIz = fmaf(wl, ev.z, cIz);
            cIw = fmaf(wl, ev.w, cIw);
            w *= a16;
        }
        // ctx entering chunk = (superchunk carry) * a16^jj + intra part
        const float a32 = a16 * a16;
        const float wj  = (jj == 1) ? a16 : (jj == 2) ? a32 : a32 * a16;
        ccx = fmaf(wj, ccx, cIx);
        ccy = fmaf(wj, ccy, cIy);
        ccz = fmaf(wj, ccz, cIz);
        ccw = fmaf(wj, ccw, cIw);
    }

    // ---- pass A: cumsum chain from registers -----------------------------
    float r[LL];
    #pragma unroll
    for (int i = 0; i < LL; i++) {
        float4 x = hv[i];
        cox += x.x; coy += x.y; coz += x.z; cow += x.w;
        float dx = cox - px, dy = coy - py, dz = coz - pz, dw = cow - pw;
        r[i] = dx * dx + dy * dy + dz * dz + dw * dw;
        px = x.x; py = x.y; pz = x.z; pw = x.w;
    }

    // batched butterfly: 6 rounds x 16 independent values (within wave)
    #pragma unroll
    for (int m = 1; m < 64; m <<= 1) {
        #pragma unroll
        for (int i = 0; i < LL; i++) r[i] += __shfl_xor(r[i], m, 64);
    }
    if (lane == 0) {
        #pragma unroll
        for (int i = 0; i < LL; i++) part[jj][gw][i] = r[i];
    }
    __syncthreads();

    float mag[LL];
    #pragma unroll
    for (int i = 0; i < LL; i++) mag[i] = sqrtf(part[jj][0][i] + part[jj][1][i]);

    // ---- pass B: ctx recurrence from registers, non-temporal store -------
    floatx4* op = reinterpret_cast<floatx4*>(out)
                + (size_t)(b * TT + t0) * D4 + col;
    #pragma unroll
    for (int i = 0; i < LL; i++) {
        float4 x = hv[i];
        ccx = fmaf(a, ccx, x.x);
        ccy = fmaf(a, ccy, x.y);
        ccz = fmaf(a, ccz, x.z);
        ccw = fmaf(a, ccw, x.w);
        float m = mag[i];
        floatx4 o;
        o.x = fabsf(m * ccx); o.y = fabsf(m * ccy);
        o.z = fabsf(m * ccz); o.w = fabsf(m * ccw);
        __builtin_nontemporal_store(o, op + (size_t)i * D4);
    }
}

extern "C" void kernel_launch(void* const* d_in, const int* in_sizes, int n_in,
                              void* d_out, int out_size, void* d_ws, size_t ws_size,
                              hipStream_t stream) {
    const float* h  = (const float*)d_in[0];
    const float* kp = (const float*)d_in[1];
    float* out = (float*)d_out;

    const size_t NSb = (size_t)BB * NSC * DD;   // 128K floats = 512 KB each
    float* ssum = (float*)d_ws;
    float* send = ssum + NSb;

    kA_stats<<<dim3(BB * NSC), dim3(4 * D4), 0, stream>>>(h, kp, ssum, send);
    kB_out  <<<dim3(BB * NSC), dim3(4 * D4), 0, stream>>>(h, kp, ssum, send, out);
}